// Round 4
// baseline (428.299 us; speedup 1.0000x reference)
//
#include <hip/hip_runtime.h>
#include <cstdint>

#define B_ 16
#define H_ 224
#define W_ 224
#define C_ 32
#define TSH 16      // output tile rows
#define TSW 32      // output tile cols
#define RGH 31      // region rows = 16 + 7 top + 8 bottom
#define RGW 47      // raw region cols = 32 + 7 left + 8 right
#define LW4 48      // f4 (4-channel) cols per LDS row; col 47 = exclusive-prefix slot
#define NSTG (RGH*LW4)   // 1488 stage slots
#define NB2  (30*LW4)    // B buffer: 30 rows

// ---- order-preserving float<->uint encoding for atomic min/max ----
__device__ __forceinline__ unsigned int enc_f(float f) {
    unsigned int u = __float_as_uint(f);
    return (u & 0x80000000u) ? ~u : (u | 0x80000000u);
}
__device__ __forceinline__ float dec_f(unsigned int u) {
    u = (u & 0x80000000u) ? (u & 0x7FFFFFFFu) : ~u;
    return __uint_as_float(u);
}

__global__ void init_ws(unsigned int* __restrict__ ws) {
    int t = threadIdx.x;
    if (t < 16) ws[t] = 0xFFFFFFFFu;
    else if (t < 32) ws[t] = 0u;
}

__global__ __launch_bounds__(256) void minmax_kernel(const float* __restrict__ x,
                                                     unsigned int* __restrict__ ws) {
    const int b = blockIdx.x;
    const int chunk = blockIdx.y;
    const int chunkElems = (H_ * W_ * C_) / 64;
    const float4* p = (const float4*)(x + (size_t)b * (H_ * W_ * C_) +
                                      (size_t)chunk * chunkElems);
    const int n4 = chunkElems / 4;
    float mn = 3.4e38f, mx = -3.4e38f;
    for (int i = threadIdx.x; i < n4; i += 256) {
        float4 v = p[i];
        mn = fminf(mn, fminf(fminf(v.x, v.y), fminf(v.z, v.w)));
        mx = fmaxf(mx, fmaxf(fmaxf(v.x, v.y), fmaxf(v.z, v.w)));
    }
#pragma unroll
    for (int off = 32; off > 0; off >>= 1) {
        mn = fminf(mn, __shfl_down(mn, off));
        mx = fmaxf(mx, __shfl_down(mx, off));
    }
    __shared__ float smn[4], smx[4];
    const int lane = threadIdx.x & 63, wv = threadIdx.x >> 6;
    if (lane == 0) { smn[wv] = mn; smx[wv] = mx; }
    __syncthreads();
    if (threadIdx.x == 0) {
        mn = fminf(fminf(smn[0], smn[1]), fminf(smn[2], smn[3]));
        mx = fmaxf(fmaxf(smx[0], smx[1]), fmaxf(smx[2], smx[3]));
        atomicMin(&ws[b], enc_f(mn));
        atomicMax(&ws[16 + b], enc_f(mx));
    }
}

// ---- float4 helpers (explicit, no reliance on operator overloads) ----
__device__ __forceinline__ float4 f4add(float4 a, float4 b) {
    return make_float4(a.x + b.x, a.y + b.y, a.z + b.z, a.w + b.w);
}
__device__ __forceinline__ float4 f4sub(float4 a, float4 b) {
    return make_float4(a.x - b.x, a.y - b.y, a.z - b.z, a.w - b.w);
}

// DPP row_shr:N accumulate: x += value of lane (i-N) within the 16-lane row (0 if OOB).
template<int N>
__device__ __forceinline__ float dpp_shr_add(float x) {
    int s = __builtin_amdgcn_update_dpp(0, __float_as_int(x), 0x110 | N, 0xF, 0xF, true);
    return x + __int_as_float(s);
}
template<int N>
__device__ __forceinline__ float4 dpp_shr_add4(float4 v) {
    v.x = dpp_shr_add<N>(v.x); v.y = dpp_shr_add<N>(v.y);
    v.z = dpp_shr_add<N>(v.z); v.w = dpp_shr_add<N>(v.w);
    return v;
}

// vertical doubling level (flat, both buffers row-major with stride LW4)
__device__ __forceinline__ void vlevel4(float4* __restrict__ dst,
                                        const float4* __restrict__ src,
                                        int rows, int sh, int tid) {
    const int nj = rows * LW4;
    for (int idx = tid; idx < nj; idx += 512)
        dst[idx] = f4add(src[idx], src[idx + sh * LW4]);
}

__device__ __forceinline__ void consume(const float4* __restrict__ buf,
                                        int row, int c0, int c1,
                                        float w, float4& acc) {
    const float4 a = buf[row * LW4 + c1];
    const float4 b = buf[row * LW4 + c0];
    acc.x += w * __log2f(fmaxf(a.x - b.x, 0.f) + 1e-7f);
    acc.y += w * __log2f(fmaxf(a.y - b.y, 0.f) + 1e-7f);
    acc.z += w * __log2f(fmaxf(a.z - b.z, 0.f) + 1e-7f);
    acc.w += w * __log2f(fmaxf(a.w - b.w, 0.f) + 1e-7f);
}

// global prefetch of one channel-group's region into registers
__device__ __forceinline__ void stage_load(const float4* __restrict__ xb4,
                                           int th0, int tw0, int ch4, int tid,
                                           float4 r[3]) {
#pragma unroll
    for (int q = 0; q < 3; ++q) {
        const int idx = tid + 512 * q;
        float4 v = make_float4(0.f, 0.f, 0.f, 0.f);
        if (idx < NSTG) {
            const int i = idx / LW4, j = idx - i * LW4;
            const int gh = th0 - 7 + i, gw = tw0 - 7 + j;
            if (j < RGW && gh >= 0 && gh < H_ && gw >= 0 && gw < W_)
                v = xb4[(size_t)(gh * W_ + gw) * (C_ / 4) + ch4];
        }
        r[q] = v;
    }
}

// lss: block = (16x32 tile, channel half). Interleaved [row][col][4ch] LDS,
// DPP horizontal prefix, ping-pong vertical doubling, register prefetch.
__global__ __launch_bounds__(512, 6) void lss_kernel(
    const float* __restrict__ x,
    const float* __restrict__ gamma, const float* __restrict__ beta,
    const float* __restrict__ mmean, const float* __restrict__ mvar,
    const unsigned int* __restrict__ ws,
    float* __restrict__ out)
{
    __shared__ float4 A4[NSTG];   // 23,808 B
    __shared__ float4 B4[NB2];    // 23,040 B

    // bi -> (tile, s) with s-halves of one tile 8 dispatches apart (same XCD via %8)
    const int bi = blockIdx.x;
    const int grp = bi >> 4, wi = bi & 15;
    const int s = (wi >> 3) & 1;
    const int t = grp * 8 + (wi & 7);          // 0..1567
    const int b = t / 98;
    const int t2 = t - b * 98;
    const int th0 = (t2 / 7) * TSH;
    const int tw0 = (t2 % 7) * TSW;
    const int tid = threadIdx.x;

    const float mn = dec_f(ws[b]);
    const float mx = dec_f(ws[16 + b]);
    const float inv = 1.0f / (mx - mn + 1e-7f);

    const float4* xb4 = (const float4*)x + (size_t)b * (H_ * W_ * C_ / 4);
    float4* ob4 = (float4*)out + (size_t)b * (H_ * W_ * C_ / 4);

    const int hl = tid >> 5, wl = tid & 31;    // output pixel owned by this thread

    float4 r[3];
    stage_load(xb4, th0, tw0, s * 4, tid, r);  // prologue: cc=0

    for (int cc = 0; cc < 4; ++cc) {
        const int ch4 = s * 4 + cc;            // f4 channel index 0..7

        __syncthreads();                       // prev consumers done with A4/B4
        // ---- stage registers -> A4 (scaled; zeros outside image / col-47 slot) ----
#pragma unroll
        for (int q = 0; q < 3; ++q) {
            const int idx = tid + 512 * q;
            if (idx < NSTG) {
                const int i = idx / LW4, j = idx - i * LW4;
                const int gh = th0 - 7 + i, gw = tw0 - 7 + j;
                const bool valid = (j < RGW) && (gh >= 0) && (gh < H_) &&
                                   (gw >= 0) && (gw < W_);
                const float4 v = r[q];
                float4 o;
                o.x = valid ? (v.x - mn) * inv : 0.f;
                o.y = valid ? (v.y - mn) * inv : 0.f;
                o.z = valid ? (v.z - mn) * inv : 0.f;
                o.w = valid ? (v.w - mn) * inv : 0.f;
                A4[idx] = o;
            }
        }
        if (cc < 3) stage_load(xb4, th0, tw0, ch4 + 1, tid, r);  // prefetch next cg
        __syncthreads();

        // ---- P1: horizontal EXCLUSIVE prefix per region row (in place) ----
        {
            const int gid = tid >> 4, il = tid & 15;
            if (gid < RGH) {
                const int base = gid * LW4 + 4 * il;
                float4 v0 = make_float4(0,0,0,0), v1 = v0, v2 = v0, v3 = v0;
                if (il < 12) { v0 = A4[base]; v1 = A4[base+1]; v2 = A4[base+2]; v3 = A4[base+3]; }
                const float4 t1 = v0;
                const float4 t2 = f4add(t1, v1);
                const float4 t3 = f4add(t2, v2);
                const float4 t4 = f4add(t3, v3);
                float4 sc = t4;                      // 16-lane inclusive scan via DPP
                sc = dpp_shr_add4<1>(sc);
                sc = dpp_shr_add4<2>(sc);
                sc = dpp_shr_add4<4>(sc);
                sc = dpp_shr_add4<8>(sc);
                const float4 carry = f4sub(sc, t4);  // exclusive carry
                if (il < 12) {
                    A4[base]     = carry;
                    A4[base + 1] = f4add(carry, t1);
                    A4[base + 2] = f4add(carry, t2);
                    A4[base + 3] = f4add(carry, t3);
                }
            }
        }
        __syncthreads();

        // ---- VH2 = E[r] + E[r+1]  (A -> B, rows 0..29) ----
        vlevel4(B4, A4, 30, 1, tid);
        __syncthreads();

        float4 acc = make_float4(0.f, 0.f, 0.f, 0.f);

        // consume scale 2 (B) ; VH4 = VH2[r]+VH2[r+2] (B -> A, rows 0..27)
        consume(B4, hl + 7, wl + 7, wl + 9, -0.3f, acc);
        vlevel4(A4, B4, 28, 2, tid);
        __syncthreads();

        // consume scale 4 (A) ; VH8 = VH4[r]+VH4[r+4] (A -> B, rows 0..23)
        consume(A4, hl + 6, wl + 6, wl + 10, -0.1f, acc);
        vlevel4(B4, A4, 24, 4, tid);
        __syncthreads();

        // consume scale 8 (B) ; VH16 = VH8[r]+VH8[r+8] (B -> A, rows 0..15)
        consume(B4, hl + 4, wl + 4, wl + 12, 0.1f, acc);
        vlevel4(A4, B4, 16, 8, tid);
        __syncthreads();

        // consume scale 16 (A), BN, store
        consume(A4, hl, wl, wl + 16, 0.3f, acc);
        {
            const float4 g  = ((const float4*)gamma)[ch4];
            const float4 be = ((const float4*)beta)[ch4];
            const float4 mm = ((const float4*)mmean)[ch4];
            const float4 mv = ((const float4*)mvar)[ch4];
            float4 o;
            o.x = (acc.x - mm.x) * (g.x * rsqrtf(mv.x + 1e-3f)) + be.x;
            o.y = (acc.y - mm.y) * (g.y * rsqrtf(mv.y + 1e-3f)) + be.y;
            o.z = (acc.z - mm.z) * (g.z * rsqrtf(mv.z + 1e-3f)) + be.z;
            o.w = (acc.w - mm.w) * (g.w * rsqrtf(mv.w + 1e-3f)) + be.w;
            ob4[(size_t)((th0 + hl) * W_ + (tw0 + wl)) * (C_ / 4) + ch4] = o;
        }
    }
}

extern "C" void kernel_launch(void* const* d_in, const int* in_sizes, int n_in,
                              void* d_out, int out_size, void* d_ws, size_t ws_size,
                              hipStream_t stream) {
    const float* x     = (const float*)d_in[0];
    const float* gamma = (const float*)d_in[1];
    const float* beta  = (const float*)d_in[2];
    const float* mmean = (const float*)d_in[3];
    const float* mvar  = (const float*)d_in[4];
    float* out = (float*)d_out;
    unsigned int* ws = (unsigned int*)d_ws;

    hipLaunchKernelGGL(init_ws, dim3(1), dim3(64), 0, stream, ws);
    hipLaunchKernelGGL(minmax_kernel, dim3(16, 64), dim3(256), 0, stream, x, ws);
    hipLaunchKernelGGL(lss_kernel, dim3(196 * 16), dim3(512), 0, stream,
                       x, gamma, beta, mmean, mvar, ws, out);
}